// Round 13
// baseline (166.671 us; speedup 1.0000x reference)
//
#include <hip/hip_runtime.h>

typedef __bf16 bf16;
typedef __attribute__((ext_vector_type(8))) __bf16 bf16x8;
typedef __attribute__((ext_vector_type(4))) __bf16 bf16x4;
typedef __attribute__((ext_vector_type(4))) float f32x4;
typedef __attribute__((ext_vector_type(16))) float f32x16;
typedef __attribute__((ext_vector_type(4))) unsigned int u32x4;

#define DI __device__ __forceinline__

static constexpr int HID = 768;
static constexpr int SEQ = 2048;
static constexpr int NH  = 12;   // heads
static constexpr int HD  = 64;   // head dim

// async global->LDS, 16B per lane; LDS dest = wave-uniform base + lane*16
DI void gload16(const void* g, void* l) {
  __builtin_amdgcn_global_load_lds(
      (const __attribute__((address_space(1))) void*)g,
      (__attribute__((address_space(3))) void*)l, 16, 0, 0);
}
// XOR swizzle for 128B-row LDS tiles (used by qkv_gemm only)
DI int swz128(int row, int cb) { return row * 128 + (cb ^ ((row & 7) << 4)); }

DI unsigned cvtpk_bf16(float lo, float hi) {
  unsigned d;
  asm("v_cvt_pk_bf16_f32 %0, %1, %2" : "=v"(d) : "v"(lo), "v"(hi));
  return d;
}
DI void permswap(unsigned &a, unsigned &b) {
  asm("v_permlane32_swap_b32 %0, %1" : "+v"(a), "+v"(b));
}

// ------------- kernel 1: merged preproc (X->bf16 ∥ W transpose) ------------
__global__ void k_pre(const float* __restrict__ X, bf16* __restrict__ Xb, int n8,
                      const float* __restrict__ Wq, const float* __restrict__ Wk,
                      const float* __restrict__ Wv, bf16* __restrict__ WT) {
  __shared__ float t[64][65];
  int bx = blockIdx.x;
  if (bx < 3072) {
    int i = bx * blockDim.x + threadIdx.x;
    if (i >= n8) return;
    const f32x4* Xv = (const f32x4*)X;
    f32x4 a = Xv[2 * i], b = Xv[2 * i + 1];
    bf16x8 o;
    o[0] = (bf16)a[0]; o[1] = (bf16)a[1]; o[2] = (bf16)a[2]; o[3] = (bf16)a[3];
    o[4] = (bf16)b[0]; o[5] = (bf16)b[1]; o[6] = (bf16)b[2]; o[7] = (bf16)b[3];
    *(bf16x8*)(Xb + (size_t)i * 8) = o;
    return;
  }
  int tt2 = bx - 3072;                 // 0..431
  int z = tt2 / 144;
  int rem = tt2 - z * 144;
  int ny = rem / 12, kx = rem % 12;
  const float* W = (z == 0) ? Wq : (z == 1) ? Wk : Wv;
  bf16* WTz = WT + (size_t)z * HID * HID;
  int k0 = kx * 64, n0 = ny * 64;
  int tt = threadIdx.x;
  for (int p = 0; p < 4; ++p) {
    int r = p * 16 + (tt >> 4), c4 = (tt & 15) * 4;
    f32x4 v = *(const f32x4*)(W + (size_t)(k0 + r) * HID + n0 + c4);
    t[c4 + 0][r] = v[0]; t[c4 + 1][r] = v[1]; t[c4 + 2][r] = v[2]; t[c4 + 3][r] = v[3];
  }
  __syncthreads();
  for (int p = 0; p < 4; ++p) {
    int rn = p * 16 + (tt >> 4), c4 = (tt & 15) * 4;
    bf16x4 o;
    o[0] = (bf16)t[rn][c4]; o[1] = (bf16)t[rn][c4 + 1];
    o[2] = (bf16)t[rn][c4 + 2]; o[3] = (bf16)t[rn][c4 + 3];
    *(bf16x4*)(WTz + (size_t)(n0 + rn) * HID + k0 + c4) = o;
  }
}

// ---------------- kernel 3: QKV GEMM (128x128 tile, BK=64) -----------------
// R4-verified. z==0: Q row-major [BH][S][D], scaled 1/8.
// z==1: K chunked-tile [BH][kt][ch=D/8][row=s&63][8].
// z==2: V^T chunked-tile [BH][kt][ch=(s>>3)&7][row=d][8].
__global__ __launch_bounds__(256, 2)
void k_qkv_gemm(const bf16* __restrict__ Xb, const bf16* __restrict__ WT,
                const float* __restrict__ bq, const float* __restrict__ bk,
                const float* __restrict__ bv,
                bf16* __restrict__ Qb, bf16* __restrict__ Kb, bf16* __restrict__ VTb) {
  int z = blockIdx.z;
  const bf16* WTz = WT + (size_t)z * HID * HID;
  const float* bias = (z == 0) ? bq : (z == 1) ? bk : bv;

  int m0 = blockIdx.x * 128, n0 = blockIdx.y * 128;
  __shared__ char lds[32768];
  int w = threadIdx.x >> 6, l = threadIdx.x & 63;
  int wr = w >> 1, wc = w & 1;

  f32x4 acc[4][4] = {};

  for (int it = 0; it < HID / 64; ++it) {
    int k0 = it * 64;
    __syncthreads();
    for (int j = 0; j < 8; ++j) {
      int base = w * 8192 + j * 1024;
      int o = base + l * 16;
      const char* src;
      if (o < 16384) {
        int row = o >> 7;
        int cb = (o & 127) ^ ((row & 7) << 4);
        src = (const char*)(Xb + (size_t)(m0 + row) * HID + k0) + cb;
      } else {
        int o2 = o - 16384;
        int row = o2 >> 7;
        int cb = (o2 & 127) ^ ((row & 7) << 4);
        src = (const char*)(WTz + (size_t)(n0 + row) * HID + k0) + cb;
      }
      gload16(src, lds + base);
    }
    __syncthreads();

    for (int kk = 0; kk < 2; ++kk) {
      bf16x8 af[4], bfr[4];
      int cb = kk * 64 + ((l >> 4) << 4);
      for (int ms = 0; ms < 4; ++ms) {
        int row = wr * 64 + ms * 16 + (l & 15);
        af[ms] = *(const bf16x8*)(lds + swz128(row, cb));
      }
      for (int ns = 0; ns < 4; ++ns) {
        int row = wc * 64 + ns * 16 + (l & 15);
        bfr[ns] = *(const bf16x8*)(lds + 16384 + swz128(row, cb));
      }
      for (int ms = 0; ms < 4; ++ms)
        for (int ns = 0; ns < 4; ++ns)
          acc[ms][ns] = __builtin_amdgcn_mfma_f32_16x16x32_bf16(af[ms], bfr[ns], acc[ms][ns], 0, 0, 0);
    }
  }

  if (z == 2) {
    #pragma unroll
    for (int ns = 0; ns < 4; ++ns) {
      int col = n0 + wc * 64 + ns * 16 + (l & 15);
      float bvv = bias[col];
      int h = col >> 6, d = col & 63;
      #pragma unroll
      for (int ms = 0; ms < 4; ++ms) {
        int m = m0 + wr * 64 + ms * 16 + ((l >> 4) << 2);
        int bb = m >> 11, s = m & 2047;
        bf16x4 pk;
        #pragma unroll
        for (int r = 0; r < 4; ++r) pk[r] = (bf16)(acc[ms][ns][r] + bvv);
        size_t base = (size_t)(bb * NH + h) * HD * SEQ;
        size_t idx = base + (size_t)(s >> 6) * 4096 + (size_t)((s >> 3) & 7) * 512
                     + (size_t)d * 8 + (s & 7);
        *(bf16x4*)(VTb + idx) = pk;
      }
    }
  } else if (z == 1) {
    for (int ns = 0; ns < 4; ++ns) {
      int col = n0 + wc * 64 + ns * 16 + (l & 15);
      float bvv = bias[col];
      int h = col >> 6, d = col & 63;
      for (int ms = 0; ms < 4; ++ms) {
        for (int r = 0; r < 4; ++r) {
          int m = m0 + wr * 64 + ms * 16 + ((l >> 4) << 2) + r;
          int bb = m >> 11, s = m & 2047;
          float v = acc[ms][ns][r] + bvv;
          size_t base = (size_t)(bb * NH + h) * SEQ * HD;
          size_t idx = base + (size_t)(s >> 6) * 4096 + (size_t)(d >> 3) * 512
                       + (size_t)(s & 63) * 8 + (d & 7);
          Kb[idx] = (bf16)v;
        }
      }
    }
  } else {
    for (int ns = 0; ns < 4; ++ns) {
      int col = n0 + wc * 64 + ns * 16 + (l & 15);
      float bvv = bias[col];
      int h = col >> 6, d = col & 63;
      for (int ms = 0; ms < 4; ++ms) {
        for (int r = 0; r < 4; ++r) {
          int m = m0 + wr * 64 + ms * 16 + ((l >> 4) << 2) + r;
          int bb = m >> 11, s = m & 2047;
          float v = (acc[ms][ns][r] + bvv) * 0.125f;
          Qb[(((size_t)(bb * NH + h) * SEQ + s) << 6) + d] = (bf16)v;
        }
      }
    }
  }
}

// ---------------- kernel 4: flash attention, 8-wave kh-split ---------------
// R13: TLP lever done right. Grid is 768 blocks = exactly 3/CU, so the R12
// per-CU cap raise was moot. Instead: 512-thread blocks, 8 waves. Wave w
// owns q-group g=w>>1 (32 rows) and kh=w&1 (half the kv rows of each tile).
// Per-wave work halves, waves/CU 12 -> 24. K/V LDS tile shared by all 8
// waves (same 33KB). acc/psum combine additively across kh pairs in the
// epilogue (no running max in this softmax -> split is exact; only f32 sum
// order changes). launch_bounds(512,6) = 85-VGPR cap for 3 blocks/CU.
__global__ __launch_bounds__(512, 6)
void k_attn(const bf16* __restrict__ Qb, const bf16* __restrict__ Kb,
            const bf16* __restrict__ VTb, const float* __restrict__ mask,
            float* __restrict__ out) {
  // LDS: buf c at c*16384 {K 8K, V 8K}; epilogue overlays combine area:
  // 4 groups x 2048 f32 acc + 2 x 128 f32 denominators = 33.8KB.
  __shared__ char lds[34048];
  constexpr int NT = SEQ / 64;
  int bh = blockIdx.x;
  int b = bh / NH, h = bh % NH;
  int q0 = blockIdx.y * 128;
  int w = threadIdx.x >> 6, l = threadIdx.x & 63;
  int g = w >> 1, kh = w & 1;
  int q = l & 31, hi = l >> 5;
  const bf16* Qp = Qb + (size_t)bh * SEQ * HD;
  const char* Kbase = (const char*)(Kb + (size_t)bh * SEQ * HD);
  const char* VTbase = (const char*)(VTb + (size_t)bh * HD * SEQ);
  const float* mb = mask + (size_t)b * SEQ;

  // Q fragments (B operand): lane holds Q[q-row][d=dstep*16+hi*8+j].
  // Both waves of a kh-pair load the same rows (L1-hot).
  int sq = q0 + g * 32 + q;
  bf16x8 qf[4];
  #pragma unroll
  for (int dstep = 0; dstep < 4; ++dstep)
    qf[dstep] = *(const bf16x8*)(Qp + (size_t)sq * HD + dstep * 16 + hi * 8);

  f32x16 acc[2] = {};
  float psum = 0.f;

  // per-lane LDS frag-read base within a tile: chunk-lo bit (hi) + row (q)
  int rbase = hi * 1024 + q * 16;

  auto stage = [&](int c, int kt) {
    size_t t = (size_t)kt * 8192;
    int off = w * 1024;                      // 8 waves x 1KB each
    gload16(Kbase + t + off + l * 16, lds + c * 16384 + off);
    gload16(VTbase + t + off + l * 16, lds + c * 16384 + 8192 + off);
  };

  stage(0, 0);
  __syncthreads();

  int cur = 0;
  for (int kt = 0; kt < NT; ++kt) {
    if (kt + 1 < NT) stage(cur ^ 1, kt + 1);

    // this wave's kh mask slice only (8 f32)
    f32x4 mm[4];
    #pragma unroll
    for (int blk = 0; blk < 4; ++blk)
      mm[blk] = *(const f32x4*)(mb + kt * 64 + kh * 32 + blk * 8 + hi * 4);

    const char* Kl = lds + cur * 16384 + rbase;
    const char* Vl = lds + cur * 16384 + 8192 + rbase;

    // K frags for this kh: chunk = dstep*2+hi, row = kh*32+q -> base + imm
    bf16x8 kfh[4];
    #pragma unroll
    for (int dstep = 0; dstep < 4; ++dstep)
      kfh[dstep] = *(const bf16x8*)(Kl + dstep * 2048 + kh * 512);

    // QK^T with C initialized to the mask (folds the mask add into MFMA)
    f32x16 p;
    #pragma unroll
    for (int r = 0; r < 16; ++r) p[r] = mm[r >> 2][r & 3];
    __builtin_amdgcn_s_setprio(1);
    #pragma unroll
    for (int dstep = 0; dstep < 4; ++dstep)
      p = __builtin_amdgcn_mfma_f32_32x32x16_bf16(kfh[dstep], qf[dstep], p, 0, 0, 0);
    __builtin_amdgcn_s_setprio(0);

    // p = exp(s + m); per-lane partial denominator
    #pragma unroll
    for (int r = 0; r < 16; ++r) {
      float e = __expf(p[r]);
      p[r] = e;
      psum += e;
    }

    // pack to bf16 PV A-frags; V frags loaded just before use (liveness)
    #pragma unroll
    for (int half = 0; half < 2; ++half) {
      bf16x8 vfa = *(const bf16x8*)(Vl + (kh * 2 + half) * 2048 + 0 * 512);
      bf16x8 vfb = *(const bf16x8*)(Vl + (kh * 2 + half) * 2048 + 1 * 512);
      int base = half * 8;
      unsigned a0 = cvtpk_bf16(p[base + 0], p[base + 1]);
      unsigned a1 = cvtpk_bf16(p[base + 2], p[base + 3]);
      unsigned a2 = cvtpk_bf16(p[base + 4], p[base + 5]);
      unsigned a3 = cvtpk_bf16(p[base + 6], p[base + 7]);
      permswap(a0, a2);
      permswap(a1, a3);
      u32x4 pk; pk[0] = a0; pk[1] = a1; pk[2] = a2; pk[3] = a3;
      bf16x8 PA = __builtin_bit_cast(bf16x8, pk);
      __builtin_amdgcn_s_setprio(1);
      acc[0] = __builtin_amdgcn_mfma_f32_32x32x16_bf16(PA, vfa, acc[0], 0, 0, 0);
      acc[1] = __builtin_amdgcn_mfma_f32_32x32x16_bf16(PA, vfb, acc[1], 0, 0, 0);
      __builtin_amdgcn_s_setprio(0);
    }

    __syncthreads();  // next buffer staged; all reads of cur done
    cur ^= 1;
  }

  // ---- epilogue: kh-pair combine (additive), then normalize ----
  float tot = psum + __shfl_xor(psum, 32);
  float* ldsf = (float*)lds;
  if (kh == 1) {
    // write partial acc (conflict-free: lane-contiguous) + partial denom
    #pragma unroll
    for (int db = 0; db < 2; ++db)
      #pragma unroll
      for (int r = 0; r < 16; ++r)
        ldsf[g * 2048 + db * 1024 + r * 64 + l] = acc[db][r];
    if (l < 32) ldsf[8192 + g * 32 + l] = tot;
  }
  __syncthreads();
  if (kh == 0) {
    #pragma unroll
    for (int db = 0; db < 2; ++db)
      #pragma unroll
      for (int r = 0; r < 16; ++r)
        acc[db][r] += ldsf[g * 2048 + db * 1024 + r * 64 + l];
    if (l < 32) ldsf[8192 + 128 + g * 32 + l] = tot + ldsf[8192 + g * 32 + l];
  }
  __syncthreads();
  if (kh == 0) {
    f32x4 lv[4];
    #pragma unroll
    for (int blk = 0; blk < 4; ++blk)
      lv[blk] = *(const f32x4*)(ldsf + 8192 + 128 + g * 32 + blk * 8 + hi * 4);
    float inv[16];
    #pragma unroll
    for (int r = 0; r < 16; ++r) inv[r] = 1.0f / lv[r >> 2][r & 3];

    #pragma unroll
    for (int db = 0; db < 2; ++db)
      #pragma unroll
      for (int r = 0; r < 16; ++r) {
        int s = q0 + g * 32 + (r & 3) + 8 * (r >> 2) + 4 * hi;
        out[((size_t)(b * SEQ + s)) * HID + h * HD + db * 32 + q] = acc[db][r] * inv[r];
      }
  }
}

extern "C" void kernel_launch(void* const* d_in, const int* in_sizes, int n_in,
                              void* d_out, int out_size, void* d_ws, size_t ws_size,
                              hipStream_t stream) {
  const float* X    = (const float*)d_in[0];
  const float* mask = (const float*)d_in[1];
  const float* Wq   = (const float*)d_in[2];
  const float* bq   = (const float*)d_in[3];
  const float* Wk   = (const float*)d_in[4];
  const float* bk   = (const float*)d_in[5];
  const float* Wv   = (const float*)d_in[6];
  const float* bv   = (const float*)d_in[7];
  float* out = (float*)d_out;
  char* ws = (char*)d_ws;

  const size_t SZ_XB = (size_t)8192 * HID * 2;
  const size_t SZ_WT = (size_t)3 * HID * HID * 2;
  const size_t SZ_M  = (size_t)4 * NH * SEQ * HD * 2;
  bf16* Xb  = (bf16*)(ws);
  bf16* WT  = (bf16*)(ws + SZ_XB);
  bf16* Qb  = (bf16*)(ws + SZ_XB + SZ_WT);
  bf16* Kb  = (bf16*)(ws + SZ_XB + SZ_WT + SZ_M);
  bf16* VTb = (bf16*)(ws + SZ_XB + SZ_WT + 2 * SZ_M);

  k_pre<<<3504, 256, 0, stream>>>(X, Xb, 8192 * HID / 8, Wq, Wk, Wv, WT);
  k_qkv_gemm<<<dim3(64, 6, 3), 256, 0, stream>>>(Xb, WT, bq, bk, bv, Qb, Kb, VTb);
  k_attn<<<dim3(48, 16), 512, 0, stream>>>(Qb, Kb, VTb, mask, out);
}

// Round 14
// 113.688 us; speedup vs baseline: 1.4660x; 1.4660x over previous
//
#include <hip/hip_runtime.h>

typedef __bf16 bf16;
typedef __attribute__((ext_vector_type(8))) __bf16 bf16x8;
typedef __attribute__((ext_vector_type(4))) __bf16 bf16x4;
typedef __attribute__((ext_vector_type(4))) float f32x4;
typedef __attribute__((ext_vector_type(16))) float f32x16;
typedef __attribute__((ext_vector_type(4))) unsigned int u32x4;

#define DI __device__ __forceinline__

static constexpr int HID = 768;
static constexpr int SEQ = 2048;
static constexpr int NH  = 12;   // heads
static constexpr int HD  = 64;   // head dim

// async global->LDS, 16B per lane; LDS dest = wave-uniform base + lane*16
DI void gload16(const void* g, void* l) {
  __builtin_amdgcn_global_load_lds(
      (const __attribute__((address_space(1))) void*)g,
      (__attribute__((address_space(3))) void*)l, 16, 0, 0);
}
// XOR swizzle for 128B-row LDS tiles (used by qkv_gemm only)
DI int swz128(int row, int cb) { return row * 128 + (cb ^ ((row & 7) << 4)); }

DI unsigned cvtpk_bf16(float lo, float hi) {
  unsigned d;
  asm("v_cvt_pk_bf16_f32 %0, %1, %2" : "=v"(d) : "v"(lo), "v"(hi));
  return d;
}
DI void permswap(unsigned &a, unsigned &b) {
  asm("v_permlane32_swap_b32 %0, %1" : "+v"(a), "+v"(b));
}

// ------------- kernel 1: merged preproc (X->bf16 ∥ W transpose) ------------
__global__ void k_pre(const float* __restrict__ X, bf16* __restrict__ Xb, int n8,
                      const float* __restrict__ Wq, const float* __restrict__ Wk,
                      const float* __restrict__ Wv, bf16* __restrict__ WT) {
  __shared__ float t[64][65];
  int bx = blockIdx.x;
  if (bx < 3072) {
    int i = bx * blockDim.x + threadIdx.x;
    if (i >= n8) return;
    const f32x4* Xv = (const f32x4*)X;
    f32x4 a = Xv[2 * i], b = Xv[2 * i + 1];
    bf16x8 o;
    o[0] = (bf16)a[0]; o[1] = (bf16)a[1]; o[2] = (bf16)a[2]; o[3] = (bf16)a[3];
    o[4] = (bf16)b[0]; o[5] = (bf16)b[1]; o[6] = (bf16)b[2]; o[7] = (bf16)b[3];
    *(bf16x8*)(Xb + (size_t)i * 8) = o;
    return;
  }
  int tt2 = bx - 3072;                 // 0..431
  int z = tt2 / 144;
  int rem = tt2 - z * 144;
  int ny = rem / 12, kx = rem % 12;
  const float* W = (z == 0) ? Wq : (z == 1) ? Wk : Wv;
  bf16* WTz = WT + (size_t)z * HID * HID;
  int k0 = kx * 64, n0 = ny * 64;
  int tt = threadIdx.x;
  for (int p = 0; p < 4; ++p) {
    int r = p * 16 + (tt >> 4), c4 = (tt & 15) * 4;
    f32x4 v = *(const f32x4*)(W + (size_t)(k0 + r) * HID + n0 + c4);
    t[c4 + 0][r] = v[0]; t[c4 + 1][r] = v[1]; t[c4 + 2][r] = v[2]; t[c4 + 3][r] = v[3];
  }
  __syncthreads();
  for (int p = 0; p < 4; ++p) {
    int rn = p * 16 + (tt >> 4), c4 = (tt & 15) * 4;
    bf16x4 o;
    o[0] = (bf16)t[rn][c4]; o[1] = (bf16)t[rn][c4 + 1];
    o[2] = (bf16)t[rn][c4 + 2]; o[3] = (bf16)t[rn][c4 + 3];
    *(bf16x4*)(WTz + (size_t)(n0 + rn) * HID + k0 + c4) = o;
  }
}

// ---------------- kernel 3: QKV GEMM (128x128 tile, BK=64) -----------------
// R4-verified. z==0: Q row-major [BH][S][D], scaled 1/8.
// z==1: K chunked-tile [BH][kt][ch=D/8][row=s&63][8].
// z==2: V^T chunked-tile [BH][kt][ch=(s>>3)&7][row=d][8].
__global__ __launch_bounds__(256, 2)
void k_qkv_gemm(const bf16* __restrict__ Xb, const bf16* __restrict__ WT,
                const float* __restrict__ bq, const float* __restrict__ bk,
                const float* __restrict__ bv,
                bf16* __restrict__ Qb, bf16* __restrict__ Kb, bf16* __restrict__ VTb) {
  int z = blockIdx.z;
  const bf16* WTz = WT + (size_t)z * HID * HID;
  const float* bias = (z == 0) ? bq : (z == 1) ? bk : bv;

  int m0 = blockIdx.x * 128, n0 = blockIdx.y * 128;
  __shared__ char lds[32768];
  int w = threadIdx.x >> 6, l = threadIdx.x & 63;
  int wr = w >> 1, wc = w & 1;

  f32x4 acc[4][4] = {};

  for (int it = 0; it < HID / 64; ++it) {
    int k0 = it * 64;
    __syncthreads();
    for (int j = 0; j < 8; ++j) {
      int base = w * 8192 + j * 1024;
      int o = base + l * 16;
      const char* src;
      if (o < 16384) {
        int row = o >> 7;
        int cb = (o & 127) ^ ((row & 7) << 4);
        src = (const char*)(Xb + (size_t)(m0 + row) * HID + k0) + cb;
      } else {
        int o2 = o - 16384;
        int row = o2 >> 7;
        int cb = (o2 & 127) ^ ((row & 7) << 4);
        src = (const char*)(WTz + (size_t)(n0 + row) * HID + k0) + cb;
      }
      gload16(src, lds + base);
    }
    __syncthreads();

    for (int kk = 0; kk < 2; ++kk) {
      bf16x8 af[4], bfr[4];
      int cb = kk * 64 + ((l >> 4) << 4);
      for (int ms = 0; ms < 4; ++ms) {
        int row = wr * 64 + ms * 16 + (l & 15);
        af[ms] = *(const bf16x8*)(lds + swz128(row, cb));
      }
      for (int ns = 0; ns < 4; ++ns) {
        int row = wc * 64 + ns * 16 + (l & 15);
        bfr[ns] = *(const bf16x8*)(lds + 16384 + swz128(row, cb));
      }
      for (int ms = 0; ms < 4; ++ms)
        for (int ns = 0; ns < 4; ++ns)
          acc[ms][ns] = __builtin_amdgcn_mfma_f32_16x16x32_bf16(af[ms], bfr[ns], acc[ms][ns], 0, 0, 0);
    }
  }

  if (z == 2) {
    #pragma unroll
    for (int ns = 0; ns < 4; ++ns) {
      int col = n0 + wc * 64 + ns * 16 + (l & 15);
      float bvv = bias[col];
      int h = col >> 6, d = col & 63;
      #pragma unroll
      for (int ms = 0; ms < 4; ++ms) {
        int m = m0 + wr * 64 + ms * 16 + ((l >> 4) << 2);
        int bb = m >> 11, s = m & 2047;
        bf16x4 pk;
        #pragma unroll
        for (int r = 0; r < 4; ++r) pk[r] = (bf16)(acc[ms][ns][r] + bvv);
        size_t base = (size_t)(bb * NH + h) * HD * SEQ;
        size_t idx = base + (size_t)(s >> 6) * 4096 + (size_t)((s >> 3) & 7) * 512
                     + (size_t)d * 8 + (s & 7);
        *(bf16x4*)(VTb + idx) = pk;
      }
    }
  } else if (z == 1) {
    for (int ns = 0; ns < 4; ++ns) {
      int col = n0 + wc * 64 + ns * 16 + (l & 15);
      float bvv = bias[col];
      int h = col >> 6, d = col & 63;
      for (int ms = 0; ms < 4; ++ms) {
        for (int r = 0; r < 4; ++r) {
          int m = m0 + wr * 64 + ms * 16 + ((l >> 4) << 2) + r;
          int bb = m >> 11, s = m & 2047;
          float v = acc[ms][ns][r] + bvv;
          size_t base = (size_t)(bb * NH + h) * SEQ * HD;
          size_t idx = base + (size_t)(s >> 6) * 4096 + (size_t)(d >> 3) * 512
                       + (size_t)(s & 63) * 8 + (d & 7);
          Kb[idx] = (bf16)v;
        }
      }
    }
  } else {
    for (int ns = 0; ns < 4; ++ns) {
      int col = n0 + wc * 64 + ns * 16 + (l & 15);
      float bvv = bias[col];
      int h = col >> 6, d = col & 63;
      for (int ms = 0; ms < 4; ++ms) {
        for (int r = 0; r < 4; ++r) {
          int m = m0 + wr * 64 + ms * 16 + ((l >> 4) << 2) + r;
          int bb = m >> 11, s = m & 2047;
          float v = (acc[ms][ns][r] + bvv) * 0.125f;
          Qb[(((size_t)(bb * NH + h) * SEQ + s) << 6) + d] = (bf16)v;
        }
      }
    }
  }
}

// ---------------- kernel 4: flash attention, 32x32 swapped-QK^T ------------
// R14: R12's verified double-buffer loop + two critical-path cuts:
//  (1) MASK IN LDS: the 8KB mask row is staged ONCE in the prologue
//      (linear gload16); per-kt mask reads become broadcast ds_read_b128
//      on lgkmcnt — off the vmcnt staging path entirely.
//  (2) PSUM CHAIN SPLIT: 4 accumulators (static-indexed) break the
//      32-long dependent add chain per kt (FP regroup only).
// LDS 41.5KB -> still 3 blocks/CU. Everything else identical to R12.
__global__ __launch_bounds__(256, 3)
void k_attn(const bf16* __restrict__ Qb, const bf16* __restrict__ Kb,
            const bf16* __restrict__ VTb, const float* __restrict__ mask,
            float* __restrict__ out) {
  // LDS: buf0 @0, buf1 @16384 (each {K 8K, V 8K}); mask @32768 (8K);
  // lsum @40960 (512B). Total 41472.
  __shared__ char lds[41472];
  constexpr int NT = SEQ / 64;
  int bh = blockIdx.x;
  int b = bh / NH, h = bh % NH;
  int q0 = blockIdx.y * 128;
  int w = threadIdx.x >> 6, l = threadIdx.x & 63;
  int q = l & 31, hi = l >> 5;
  const bf16* Qp = Qb + (size_t)bh * SEQ * HD;
  const char* Kbase = (const char*)(Kb + (size_t)bh * SEQ * HD);
  const char* VTbase = (const char*)(VTb + (size_t)bh * HD * SEQ);
  const float* mb = mask + (size_t)b * SEQ;

  // Q fragments (B operand): lane holds Q[q=l&31][d=dstep*16+hi*8+j]
  bf16x8 qf[4];
  #pragma unroll
  for (int dstep = 0; dstep < 4; ++dstep)
    qf[dstep] = *(const bf16x8*)(Qp + (size_t)(q0 + w * 32 + q) * HD + dstep * 16 + hi * 8);

  f32x16 acc[2] = {};
  float ps0 = 0.f, ps1 = 0.f, ps2 = 0.f, ps3 = 0.f;

  // per-lane LDS frag-read base within a tile: chunk-lo bit (hi) + row (q)
  int rbase = hi * 1024 + q * 16;

  auto stage = [&](int c, int kt) {
    size_t t = (size_t)kt * 8192;
    int off = w * 2048;
    #pragma unroll
    for (int j = 0; j < 2; ++j)
      gload16(Kbase + t + off + j * 1024 + l * 16,
              lds + c * 16384 + off + j * 1024);
    #pragma unroll
    for (int j = 0; j < 2; ++j)
      gload16(VTbase + t + off + j * 1024 + l * 16,
              lds + c * 16384 + 8192 + off + j * 1024);
  };

  // prologue: stage the full 8KB mask row (linear) + tile 0
  {
    int off = w * 2048;
    #pragma unroll
    for (int j = 0; j < 2; ++j)
      gload16((const char*)mb + off + j * 1024 + l * 16,
              lds + 32768 + off + j * 1024);
  }
  stage(0, 0);
  __syncthreads();

  const float* mlds = (const float*)(lds + 32768);

  int cur = 0;
  for (int kt = 0; kt < NT; ++kt) {
    if (kt + 1 < NT) stage(cur ^ 1, kt + 1);

    // mask tile from LDS (broadcast ds_read_b128, lgkm not vmcnt)
    f32x4 mm[2][4];
    #pragma unroll
    for (int kh = 0; kh < 2; ++kh)
      #pragma unroll
      for (int blk = 0; blk < 4; ++blk)
        mm[kh][blk] = *(const f32x4*)(mlds + kt * 64 + kh * 32 + blk * 8 + hi * 4);

    const char* Kl = lds + cur * 16384 + rbase;
    const char* Vl = lds + cur * 16384 + 8192 + rbase;

    #pragma unroll
    for (int kh = 0; kh < 2; ++kh) {
      // K frag: chunk = dstep*2+hi, row = kh*32+q  -> base + imm
      // V frag: chunk = (kh*2+half)*2+hi, row = db*32+q -> base + imm
      bf16x8 kfh[4], vfk[4];
      #pragma unroll
      for (int dstep = 0; dstep < 4; ++dstep)
        kfh[dstep] = *(const bf16x8*)(Kl + dstep * 2048 + kh * 512);
      #pragma unroll
      for (int half = 0; half < 2; ++half)
        #pragma unroll
        for (int db = 0; db < 2; ++db)
          vfk[half * 2 + db] =
              *(const bf16x8*)(Vl + (kh * 2 + half) * 2048 + db * 512);

      // QK^T with C initialized to the mask (folds the mask add into MFMA)
      f32x16 p;
      #pragma unroll
      for (int r = 0; r < 16; ++r) p[r] = mm[kh][r >> 2][r & 3];
      __builtin_amdgcn_s_setprio(1);
      #pragma unroll
      for (int dstep = 0; dstep < 4; ++dstep)
        p = __builtin_amdgcn_mfma_f32_32x32x16_bf16(kfh[dstep], qf[dstep], p, 0, 0, 0);
      __builtin_amdgcn_s_setprio(0);

      // p = exp(s + m); 4-way split partial denominators (static index)
      #pragma unroll
      for (int r = 0; r < 16; ++r) {
        float e = __expf(p[r]);
        p[r] = e;
        if ((r & 3) == 0) ps0 += e;
        else if ((r & 3) == 1) ps1 += e;
        else if ((r & 3) == 2) ps2 += e;
        else ps3 += e;
      }

      // pack to bf16 PV A-frags: 4 cvt_pk + 2 permlane swaps per 16-k step
      #pragma unroll
      for (int half = 0; half < 2; ++half) {
        int base = half * 8;
        unsigned a0 = cvtpk_bf16(p[base + 0], p[base + 1]);
        unsigned a1 = cvtpk_bf16(p[base + 2], p[base + 3]);
        unsigned a2 = cvtpk_bf16(p[base + 4], p[base + 5]);
        unsigned a3 = cvtpk_bf16(p[base + 6], p[base + 7]);
        permswap(a0, a2);
        permswap(a1, a3);
        u32x4 pk; pk[0] = a0; pk[1] = a1; pk[2] = a2; pk[3] = a3;
        bf16x8 PA = __builtin_bit_cast(bf16x8, pk);
        __builtin_amdgcn_s_setprio(1);
        #pragma unroll
        for (int db = 0; db < 2; ++db)
          acc[db] = __builtin_amdgcn_mfma_f32_32x32x16_bf16(PA, vfk[half * 2 + db], acc[db], 0, 0, 0);
        __builtin_amdgcn_s_setprio(0);
      }
    }

    __syncthreads();  // next buffer staged; all reads of cur done
    cur ^= 1;
  }

  // epilogue: full denominator per q (= l&31) then redistribute to acc rows
  float psum = (ps0 + ps1) + (ps2 + ps3);
  float tot = psum + __shfl_xor(psum, 32);
  float* lsumL = (float*)(lds + 40960 + w * 128);
  if (l < 32) lsumL[l] = tot;
  __syncthreads();
  f32x4 lv[4];
  #pragma unroll
  for (int blk = 0; blk < 4; ++blk)
    lv[blk] = *(const f32x4*)(lsumL + blk * 8 + hi * 4);
  float inv[16];
  #pragma unroll
  for (int r = 0; r < 16; ++r) inv[r] = 1.0f / lv[r >> 2][r & 3];

  #pragma unroll
  for (int db = 0; db < 2; ++db)
    #pragma unroll
    for (int r = 0; r < 16; ++r) {
      int s = q0 + w * 32 + (r & 3) + 8 * (r >> 2) + 4 * hi;
      out[((size_t)(b * SEQ + s)) * HID + h * HD + db * 32 + q] = acc[db][r] * inv[r];
    }
}

extern "C" void kernel_launch(void* const* d_in, const int* in_sizes, int n_in,
                              void* d_out, int out_size, void* d_ws, size_t ws_size,
                              hipStream_t stream) {
  const float* X    = (const float*)d_in[0];
  const float* mask = (const float*)d_in[1];
  const float* Wq   = (const float*)d_in[2];
  const float* bq   = (const float*)d_in[3];
  const float* Wk   = (const float*)d_in[4];
  const float* bk   = (const float*)d_in[5];
  const float* Wv   = (const float*)d_in[6];
  const float* bv   = (const float*)d_in[7];
  float* out = (float*)d_out;
  char* ws = (char*)d_ws;

  const size_t SZ_XB = (size_t)8192 * HID * 2;
  const size_t SZ_WT = (size_t)3 * HID * HID * 2;
  const size_t SZ_M  = (size_t)4 * NH * SEQ * HD * 2;
  bf16* Xb  = (bf16*)(ws);
  bf16* WT  = (bf16*)(ws + SZ_XB);
  bf16* Qb  = (bf16*)(ws + SZ_XB + SZ_WT);
  bf16* Kb  = (bf16*)(ws + SZ_XB + SZ_WT + SZ_M);
  bf16* VTb = (bf16*)(ws + SZ_XB + SZ_WT + 2 * SZ_M);

  k_pre<<<3504, 256, 0, stream>>>(X, Xb, 8192 * HID / 8, Wq, Wk, Wv, WT);
  k_qkv_gemm<<<dim3(64, 6, 3), 256, 0, stream>>>(Xb, WT, bq, bk, bv, Qb, Kb, VTb);
  k_attn<<<dim3(48, 16), 256, 0, stream>>>(Qb, Kb, VTb, mask, out);
}